// Round 12
// baseline (322.699 us; speedup 1.0000x reference)
//
#include <hip/hip_runtime.h>
#include <cstddef>

static constexpr float ALPHA = 0.2f;
static constexpr int H = 64;
static constexpr int BSH = 9;        // bucket = 512 nodes
static constexpr int NBMAX = 512;    // max combined buckets
static constexpr int BTILE = 2048;   // bfill edges per block (8/thread)

typedef __attribute__((ext_vector_type(8))) short short8;
typedef __attribute__((ext_vector_type(4))) float floatx4;

__device__ __forceinline__ float lrelu(float v) { return v >= 0.0f ? v : ALPHA * v; }

__device__ __forceinline__ float b2f(unsigned short u)
{
    union { unsigned int i; float f; } x;
    x.i = ((unsigned int)u) << 16;
    return x.f;
}

__device__ __forceinline__ unsigned short f2b(float f)
{
    union { float f; unsigned int i; } x;
    x.f = f;
    unsigned int r = x.i + 0x7fffu + ((x.i >> 16) & 1u);  // RNE
    return (unsigned short)(r >> 16);
}

// ---- MFMA GEMM: out[rows,64](bf16) = act(in[rows,K] @ W[K,64] (+bias)) (* scl[row]) ----
// CLS: additionally, for rows < clsN, emit log_softmax(lrelu(acc + clsBias) @ Wc + bc) to fout.
template <int K, bool AF32, bool BIAS, bool ACT, bool SCALE, bool CLS>
__global__ __launch_bounds__(256) void mfma_gemm(
    const void* __restrict__ in_v, const float* __restrict__ W,
    const float* __restrict__ bias, const float* __restrict__ scl,
    unsigned short* __restrict__ out, int rows,
    const float* __restrict__ clsBias, const float* __restrict__ Wc,
    const float* __restrict__ bc, float* __restrict__ fout, int clsN)
{
    constexpr int S = K / 32;
    __shared__ short8 WL[4 * S * 64];

    for (int f = threadIdx.x; f < 4 * S * 64; f += 256) {
        int c = f / (S * 64);
        int rem = f % (S * 64);
        int s = rem / 64;
        int l = rem % 64;
        short8 frag;
        #pragma unroll
        for (int j = 0; j < 8; ++j) {
            int k = s * 32 + (l >> 4) * 8 + j;
            int col = c * 16 + (l & 15);
            frag[j] = (short)f2b(W[k * H + col]);
        }
        WL[f] = frag;
    }
    __syncthreads();

    const int l = threadIdx.x & 63;
    const int wv = threadIdx.x >> 6;
    const int rowBase = blockIdx.x * 64 + wv * 16;
    if (rowBase >= rows) return;
    const int arow = min(rowBase + (l & 15), rows - 1);

    floatx4 acc0 = {0.f, 0.f, 0.f, 0.f};
    floatx4 acc1 = {0.f, 0.f, 0.f, 0.f};
    floatx4 acc2 = {0.f, 0.f, 0.f, 0.f};
    floatx4 acc3 = {0.f, 0.f, 0.f, 0.f};

    #pragma unroll
    for (int s = 0; s < S; ++s) {
        short8 a;
        if (AF32) {
            const float* ap = (const float*)in_v + (size_t)arow * K + s * 32 + (l >> 4) * 8;
            float4 f0 = *(const float4*)(ap + 0);
            float4 f1 = *(const float4*)(ap + 4);
            a[0] = (short)f2b(f0.x); a[1] = (short)f2b(f0.y);
            a[2] = (short)f2b(f0.z); a[3] = (short)f2b(f0.w);
            a[4] = (short)f2b(f1.x); a[5] = (short)f2b(f1.y);
            a[6] = (short)f2b(f1.z); a[7] = (short)f2b(f1.w);
        } else {
            a = *(const short8*)((const unsigned short*)in_v + (size_t)arow * K + s * 32 + (l >> 4) * 8);
        }
        acc0 = __builtin_amdgcn_mfma_f32_16x16x32_bf16(a, WL[(0 * S + s) * 64 + l], acc0, 0, 0, 0);
        acc1 = __builtin_amdgcn_mfma_f32_16x16x32_bf16(a, WL[(1 * S + s) * 64 + l], acc1, 0, 0, 0);
        acc2 = __builtin_amdgcn_mfma_f32_16x16x32_bf16(a, WL[(2 * S + s) * 64 + l], acc2, 0, 0, 0);
        acc3 = __builtin_amdgcn_mfma_f32_16x16x32_bf16(a, WL[(3 * S + s) * 64 + l], acc3, 0, 0, 0);
    }

    #pragma unroll
    for (int j = 0; j < 4; ++j) {
        int row = rowBase + (l >> 4) * 4 + j;
        if (row >= rows) continue;
        unsigned short* orow = out + (size_t)row * H;
        float sc = SCALE ? scl[row] : 1.0f;
        float v;
        int col = l & 15;
        v = acc0[j] + (BIAS ? bias[col] : 0.f);      if (ACT) v = lrelu(v); orow[col]      = f2b(v * sc);
        v = acc1[j] + (BIAS ? bias[col + 16] : 0.f); if (ACT) v = lrelu(v); orow[col + 16] = f2b(v * sc);
        v = acc2[j] + (BIAS ? bias[col + 32] : 0.f); if (ACT) v = lrelu(v); orow[col + 32] = f2b(v * sc);
        v = acc3[j] + (BIAS ? bias[col + 48] : 0.f); if (ACT) v = lrelu(v); orow[col + 48] = f2b(v * sc);

        if (CLS) {
            if (row < clsN) {
                float r0 = lrelu(acc0[j] + clsBias[col]);
                float r1 = lrelu(acc1[j] + clsBias[col + 16]);
                float r2 = lrelu(acc2[j] + clsBias[col + 32]);
                float r3 = lrelu(acc3[j] + clsBias[col + 48]);
                float p0 = r0 * Wc[col * 2]            + r1 * Wc[(col + 16) * 2]
                         + r2 * Wc[(col + 32) * 2]     + r3 * Wc[(col + 48) * 2];
                float p1 = r0 * Wc[col * 2 + 1]        + r1 * Wc[(col + 16) * 2 + 1]
                         + r2 * Wc[(col + 32) * 2 + 1] + r3 * Wc[(col + 48) * 2 + 1];
                #pragma unroll
                for (int o = 8; o; o >>= 1) {
                    p0 += __shfl_xor(p0, o);
                    p1 += __shfl_xor(p1, o);
                }
                if (col == 0) {
                    float l0 = p0 + bc[0], l1 = p1 + bc[1];
                    float m = fmaxf(l0, l1);
                    float lse = m + logf(expf(l0 - m) + expf(l1 - m));
                    fout[(size_t)row * 2 + 0] = l0 - lse;
                    fout[(size_t)row * 2 + 1] = l1 - lse;
                }
            }
        }
    }
}

// ---------------- combined bucket-sort CSR build (512-node buckets, data + meta) ----------------
// virtual buckets: [0, nbD) data (dst>>9), [nbD, nbD+nbM) meta.
// packed entry = (dstLocal<<17) | src   (src < 2^17, dstLocal < 512)

__global__ __launch_bounds__(256) void zero_i(int* __restrict__ p, int n)
{
    int i = blockIdx.x * 256 + threadIdx.x;
    if (i < n) p[i] = 0;
}

__global__ __launch_bounds__(256) void bhist(const int* __restrict__ dstD, const int* __restrict__ dstM,
                                             int* __restrict__ gbh, int E, int Et, int nbD, int nbT)
{
    __shared__ int lh[NBMAX];
    for (int i = threadIdx.x; i < nbT; i += 256) lh[i] = 0;
    __syncthreads();
    for (int j = blockIdx.x * 256 + threadIdx.x; j < Et; j += 256 * gridDim.x) {
        int b = (j < E) ? (dstD[j] >> BSH) : (nbD + (dstM[j - E] >> BSH));
        atomicAdd(&lh[b], 1);
    }
    __syncthreads();
    for (int b = threadIdx.x; b < nbT; b += 256) {
        int v = lh[b];
        if (v) atomicAdd(&gbh[b], v);
    }
}

// single-block exclusive scan (nb <= 512, 2 per thread)
__global__ __launch_bounds__(256) void bscan(const int* __restrict__ gbh, int* __restrict__ goff,
                                             int* __restrict__ gcur, int nb)
{
    __shared__ int sp[256];
    int t = threadIdx.x;
    int base = t * 2;
    int a0 = (base     < nb) ? gbh[base]     : 0;
    int a1 = (base + 1 < nb) ? gbh[base + 1] : 0;
    int s = a0 + a1;
    sp[t] = s;
    __syncthreads();
    for (int o = 1; o < 256; o <<= 1) {
        int y = (t >= o) ? sp[t - o] : 0;
        __syncthreads();
        sp[t] += y;
        __syncthreads();
    }
    int e = sp[t] - s;
    if (base < nb)     { goff[base] = e;          gcur[base] = e; }
    if (base + 1 < nb) { goff[base + 1] = e + a0; gcur[base + 1] = e + a0; }
}

// direct rank-scatter over the combined edge list; edges cached in registers between passes
__global__ __launch_bounds__(256) void bfill(const int* __restrict__ srcD, const int* __restrict__ dstD,
                                             const int* __restrict__ srcM, const int* __restrict__ dstM,
                                             int* __restrict__ gcur, int* __restrict__ ebuf,
                                             int E, int Et, int nbD, int nbT)
{
    __shared__ int lh[NBMAX];
    __shared__ int lst[NBMAX];
    const int t = threadIdx.x;
    const int base = blockIdx.x * BTILE;

    for (int i = t; i < nbT; i += 256) lh[i] = 0;
    __syncthreads();

    int bb[8], pk[8];
    #pragma unroll
    for (int u = 0; u < 8; ++u) {
        int j = base + u * 256 + t;
        if (j < Et) {
            int d, sv;
            if (j < E) { d = dstD[j]; sv = srcD[j]; bb[u] = d >> BSH; }
            else       { d = dstM[j - E]; sv = srcM[j - E]; bb[u] = nbD + (d >> BSH); }
            pk[u] = ((d & (NBMAX - 1)) << 17) | sv;
            atomicAdd(&lh[bb[u]], 1);
        } else bb[u] = -1;
    }
    __syncthreads();

    for (int b = t; b < nbT; b += 256) {
        int k = lh[b];
        lst[b] = k ? atomicAdd(&gcur[b], k) : 0;
    }
    __syncthreads();

    #pragma unroll
    for (int u = 0; u < 8; ++u) {
        if (bb[u] >= 0) {
            int pos = atomicAdd(&lst[bb[u]], 1);
            ebuf[pos] = pk[u];
        }
    }
}

// block per 512-node bucket: local counting sort -> esrc (dense) + rs/cnt/dis in virtual node space
__global__ __launch_bounds__(256) void local_csr(const int* __restrict__ ebuf, const int* __restrict__ goff,
                                                 const int* __restrict__ gbh, int* __restrict__ esrc,
                                                 int* __restrict__ rs, int* __restrict__ cnt,
                                                 float* __restrict__ dis, int nbD, int N, int NM)
{
    __shared__ int lcnt[512];
    __shared__ int lex[512];
    __shared__ int lcur[512];
    __shared__ int sp[256];
    const int b = blockIdx.x;
    const int t = threadIdx.x;
    const int off = goff[b];
    const int k = gbh[b];
    const bool isData = b < nbD;

    lcnt[t] = 0; lcnt[t + 256] = 0;
    __syncthreads();
    for (int i = t; i < k; i += 256) atomicAdd(&lcnt[ebuf[off + i] >> 17], 1);
    __syncthreads();
    {
        int a0 = lcnt[2 * t], a1 = lcnt[2 * t + 1];
        int s = a0 + a1;
        sp[t] = s;
        __syncthreads();
        for (int o = 1; o < 256; o <<= 1) {
            int y = (t >= o) ? sp[t - o] : 0;
            __syncthreads();
            sp[t] += y;
            __syncthreads();
        }
        int e = sp[t] - s;
        lex[2 * t] = e;          lcur[2 * t] = e;
        lex[2 * t + 1] = e + a0; lcur[2 * t + 1] = e + a0;
    }
    __syncthreads();
    for (int i = t; i < k; i += 256) {
        int v = ebuf[off + i];
        int pos = atomicAdd(&lcur[v >> 17], 1);
        esrc[off + pos] = v & 0x1FFFF;
    }
    #pragma unroll
    for (int u = 0; u < 2; ++u) {
        int nl = t + u * 256;
        int local = (isData ? b : b - nbD) * 512 + nl;
        int lim = isData ? N : NM;
        if (local < lim) {
            int slot = isData ? local : N + local;
            int c = lcnt[nl];
            rs[slot] = off + lex[nl];
            cnt[slot] = c;
            int dt = c + (isData ? 1 : 0);
            dis[slot] = dt > 0 ? rsqrtf((float)dt) : 0.0f;
        }
    }
}

// ---- 16-lanes-per-dst gather, 4-deep unrolled: 16 dst rows per block ----
// h pre-scaled by dis[src]; out = lrelu(dd*(sum hs[s] (+hs[d] if SELF)) + bias)
template <bool SELF, bool FINAL>
__global__ __launch_bounds__(256) void gather16(const unsigned short* __restrict__ h,
                                                const int* __restrict__ esrc,
                                                const int* __restrict__ rs, const int* __restrict__ cnt,
                                                const float* __restrict__ dis, const float* __restrict__ bias,
                                                unsigned short* __restrict__ out,
                                                const float* __restrict__ Wc, const float* __restrict__ bc,
                                                float* __restrict__ fout, int base, int n)
{
    int d = base + blockIdx.x * 16 + (threadIdx.x >> 4);
    if (d >= n) return;
    const int l = threadIdx.x & 15;
    const int beg = rs[d];
    const int c = cnt[d];
    const float dd = dis[d];

    float ax0 = 0.f, ay0 = 0.f, az0 = 0.f, aw0 = 0.f;
    float ax1 = 0.f, ay1 = 0.f, az1 = 0.f, aw1 = 0.f;
    float ax2 = 0.f, ay2 = 0.f, az2 = 0.f, aw2 = 0.f;
    float ax3 = 0.f, ay3 = 0.f, az3 = 0.f, aw3 = 0.f;
    int i = 0;
    for (; i + 4 <= c; i += 4) {
        int s0 = esrc[beg + i], s1 = esrc[beg + i + 1];
        int s2 = esrc[beg + i + 2], s3 = esrc[beg + i + 3];
        ushort4 v0 = *(const ushort4*)(h + (size_t)s0 * H + l * 4);
        ushort4 v1 = *(const ushort4*)(h + (size_t)s1 * H + l * 4);
        ushort4 v2 = *(const ushort4*)(h + (size_t)s2 * H + l * 4);
        ushort4 v3 = *(const ushort4*)(h + (size_t)s3 * H + l * 4);
        ax0 += b2f(v0.x); ay0 += b2f(v0.y); az0 += b2f(v0.z); aw0 += b2f(v0.w);
        ax1 += b2f(v1.x); ay1 += b2f(v1.y); az1 += b2f(v1.z); aw1 += b2f(v1.w);
        ax2 += b2f(v2.x); ay2 += b2f(v2.y); az2 += b2f(v2.z); aw2 += b2f(v2.w);
        ax3 += b2f(v3.x); ay3 += b2f(v3.y); az3 += b2f(v3.z); aw3 += b2f(v3.w);
    }
    for (; i < c; ++i) {
        int s = esrc[beg + i];
        ushort4 v = *(const ushort4*)(h + (size_t)s * H + l * 4);
        ax0 += b2f(v.x); ay0 += b2f(v.y); az0 += b2f(v.z); aw0 += b2f(v.w);
    }
    if (SELF) {
        ushort4 v = *(const ushort4*)(h + (size_t)d * H + l * 4);
        ax0 += b2f(v.x); ay0 += b2f(v.y); az0 += b2f(v.z); aw0 += b2f(v.w);
    }

    float rx = ((ax0 + ax1) + (ax2 + ax3)) * dd;
    float ry = ((ay0 + ay1) + (ay2 + ay3)) * dd;
    float rz = ((az0 + az1) + (az2 + az3)) * dd;
    float rw = ((aw0 + aw1) + (aw2 + aw3)) * dd;
    float4 bb = *(const float4*)(bias + l * 4);
    rx = lrelu(rx + bb.x); ry = lrelu(ry + bb.y); rz = lrelu(rz + bb.z); rw = lrelu(rw + bb.w);

    if (FINAL) {
        int f = l * 4;
        float p0 = rx * Wc[(f + 0) * 2] + ry * Wc[(f + 1) * 2] + rz * Wc[(f + 2) * 2] + rw * Wc[(f + 3) * 2];
        float p1 = rx * Wc[(f + 0) * 2 + 1] + ry * Wc[(f + 1) * 2 + 1] + rz * Wc[(f + 2) * 2 + 1] + rw * Wc[(f + 3) * 2 + 1];
        #pragma unroll
        for (int o = 8; o; o >>= 1) {
            p0 += __shfl_xor(p0, o);
            p1 += __shfl_xor(p1, o);
        }
        if (l == 0) {
            float l0 = p0 + bc[0], l1 = p1 + bc[1];
            float m = fmaxf(l0, l1);
            float lse = m + logf(expf(l0 - m) + expf(l1 - m));
            fout[(size_t)d * 2 + 0] = l0 - lse;
            fout[(size_t)d * 2 + 1] = l1 - lse;
        }
    } else {
        ushort4 o;
        o.x = f2b(rx); o.y = f2b(ry); o.z = f2b(rz); o.w = f2b(rw);
        *(ushort4*)(out + (size_t)d * H + l * 4) = o;
    }
}

extern "C" void kernel_launch(void* const* d_in, const int* in_sizes, int n_in,
                              void* d_out, int out_size, void* d_ws, size_t ws_size,
                              hipStream_t stream)
{
    const float* x      = (const float*)d_in[0];
    const int*   ei     = (const int*)d_in[1];
    const float* mx     = (const float*)d_in[2];
    const int*   mei    = (const int*)d_in[3];
    const float* W_lin  = (const float*)d_in[4];
    const float* b_lin  = (const float*)d_in[5];
    const float* W_mlin = (const float*)d_in[6];
    const float* b_mlin = (const float*)d_in[7];
    const float* W0     = (const float*)d_in[8];
    const float* b0     = (const float*)d_in[9];
    const float* W1     = (const float*)d_in[10];
    const float* b1     = (const float*)d_in[11];
    const float* Wm     = (const float*)d_in[12];
    const float* bm     = (const float*)d_in[13];
    const float* Wc     = (const float*)d_in[14];
    const float* bc     = (const float*)d_in[15];

    const int F  = 128;
    const int N  = in_sizes[0] / F;
    const int E  = in_sizes[1] / 2;
    const int M  = in_sizes[2] / F;
    const int Em = in_sizes[3] / 2;
    const int NM = N + M;
    const int Et = E + Em;
    const int* src  = ei;
    const int* dstp = ei + E;
    const int* msrc = mei;
    const int* mdst = mei + Em;

    unsigned short* hb0 = (unsigned short*)d_ws;        // [NM, H] bf16
    unsigned short* hb1 = hb0 + (size_t)NM * H;         // [NM, H] bf16
    float* disV = (float*)(hb1 + (size_t)NM * H);       // [N + NM]
    int*   cntV = (int*)(disV + (N + NM));              // [N + NM]
    int*   rsV  = cntV + (N + NM);                      // [N + NM]
    int*   esrcA = rsV + (N + NM);                      // [Et]
    int*   ebuf  = esrcA + Et;                          // [Et]
    int*   gbh  = ebuf + Et;                            // [NBMAX]
    int*   goff = gbh + NBMAX;                          // [NBMAX]
    int*   gcur = goff + NBMAX;                         // [NBMAX]

    const int nbD = (N + 511) / 512;
    const int nbM = (NM + 511) / 512;
    const int nbT = nbD + nbM;

    // input projections (meta rows go straight to concat slot)
    mfma_gemm<128, true, true, true, false, false><<<(N + 63) / 64, 256, 0, stream>>>(
        x, W_lin, b_lin, nullptr, hb0, N, nullptr, nullptr, nullptr, nullptr, 0);
    mfma_gemm<128, true, true, true, false, false><<<(M + 63) / 64, 256, 0, stream>>>(
        mx, W_mlin, b_mlin, nullptr, hb0 + (size_t)N * H, M, nullptr, nullptr, nullptr, nullptr, 0);

    // combined CSR build (data + meta graphs in one pass)
    zero_i<<<(NBMAX + 255) / 256, 256, 0, stream>>>(gbh, NBMAX);
    bhist<<<256, 256, 0, stream>>>(dstp, mdst, gbh, E, Et, nbD, nbT);
    bscan<<<1, 256, 0, stream>>>(gbh, goff, gcur, nbT);
    bfill<<<(Et + BTILE - 1) / BTILE, 256, 0, stream>>>(src, dstp, msrc, mdst, gcur, ebuf, E, Et, nbD, nbT);
    local_csr<<<nbT, 256, 0, stream>>>(ebuf, goff, gbh, esrcA, rsV, cntV, disV, nbD, N, NM);

    // GCN layer 0 (GEMM output pre-scaled by dis)
    mfma_gemm<64, false, false, false, true, false><<<(N + 63) / 64, 256, 0, stream>>>(
        hb0, W0, nullptr, disV, hb1, N, nullptr, nullptr, nullptr, nullptr, 0);
    gather16<true, false><<<(N + 15) / 16, 256, 0, stream>>>(
        hb1, esrcA, rsV, cntV, disV, b0, hb0, nullptr, nullptr, nullptr, 0, N);

    // GCN layer 1
    mfma_gemm<64, false, false, false, true, false><<<(N + 63) / 64, 256, 0, stream>>>(
        hb0, W1, nullptr, disV, hb1, N, nullptr, nullptr, nullptr, nullptr, 0);
    gather16<true, false><<<(N + 15) / 16, 256, 0, stream>>>(
        hb1, esrcA, rsV, cntV, disV, b1, hb0, nullptr, nullptr, nullptr, 0, N);

    // meta fusion GEMM over z = hb0[0..NM), pre-scaled by meta dis.
    // Data rows (< N) have deg=1 self-loop in the meta graph (dis=1), so their final
    // output is log_softmax(lrelu(acc + bm) @ Wc + bc) — fused into this epilogue.
    mfma_gemm<64, false, false, false, true, true><<<(NM + 63) / 64, 256, 0, stream>>>(
        hb0, Wm, nullptr, disV + N, hb1, NM, bm, Wc, bc, (float*)d_out, N);

    // final gather + fused classifier + log_softmax over META nodes only (d in [N, NM))
    gather16<false, true><<<(M + 15) / 16, 256, 0, stream>>>(
        hb1, esrcA, rsV + N, cntV + N, disV + N, bm, nullptr, Wc, bc, (float*)d_out, N, NM);
}

// Round 13
// 253.514 us; speedup vs baseline: 1.2729x; 1.2729x over previous
//
#include <hip/hip_runtime.h>
#include <cstddef>

static constexpr float ALPHA = 0.2f;
static constexpr int H = 64;
static constexpr int NBMAX = 2048;   // combined buckets (128 nodes each)
static constexpr int BTILE = 2048;   // bfill edges per block (8/thread)

typedef __attribute__((ext_vector_type(8))) short short8;
typedef __attribute__((ext_vector_type(4))) float floatx4;

__device__ __forceinline__ float lrelu(float v) { return v >= 0.0f ? v : ALPHA * v; }

__device__ __forceinline__ float b2f(unsigned short u)
{
    union { unsigned int i; float f; } x;
    x.i = ((unsigned int)u) << 16;
    return x.f;
}

__device__ __forceinline__ unsigned short f2b(float f)
{
    union { float f; unsigned int i; } x;
    x.f = f;
    unsigned int r = x.i + 0x7fffu + ((x.i >> 16) & 1u);  // RNE
    return (unsigned short)(r >> 16);
}

// ---- MFMA GEMM: out[rows,64](bf16) = act(in[rows,K] @ W[K,64] (+bias)) (* scl[row]) ----
// CLS: additionally, for rows < clsN, emit log_softmax(lrelu(acc + clsBias) @ Wc + bc) to fout.
template <int K, bool AF32, bool BIAS, bool ACT, bool SCALE, bool CLS>
__global__ __launch_bounds__(256) void mfma_gemm(
    const void* __restrict__ in_v, const float* __restrict__ W,
    const float* __restrict__ bias, const float* __restrict__ scl,
    unsigned short* __restrict__ out, int rows,
    const float* __restrict__ clsBias, const float* __restrict__ Wc,
    const float* __restrict__ bc, float* __restrict__ fout, int clsN)
{
    constexpr int S = K / 32;
    __shared__ short8 WL[4 * S * 64];

    for (int f = threadIdx.x; f < 4 * S * 64; f += 256) {
        int c = f / (S * 64);
        int rem = f % (S * 64);
        int s = rem / 64;
        int l = rem % 64;
        short8 frag;
        #pragma unroll
        for (int j = 0; j < 8; ++j) {
            int k = s * 32 + (l >> 4) * 8 + j;
            int col = c * 16 + (l & 15);
            frag[j] = (short)f2b(W[k * H + col]);
        }
        WL[f] = frag;
    }
    __syncthreads();

    const int l = threadIdx.x & 63;
    const int wv = threadIdx.x >> 6;
    const int rowBase = blockIdx.x * 64 + wv * 16;
    if (rowBase >= rows) return;
    const int arow = min(rowBase + (l & 15), rows - 1);

    floatx4 acc0 = {0.f, 0.f, 0.f, 0.f};
    floatx4 acc1 = {0.f, 0.f, 0.f, 0.f};
    floatx4 acc2 = {0.f, 0.f, 0.f, 0.f};
    floatx4 acc3 = {0.f, 0.f, 0.f, 0.f};

    #pragma unroll
    for (int s = 0; s < S; ++s) {
        short8 a;
        if (AF32) {
            const float* ap = (const float*)in_v + (size_t)arow * K + s * 32 + (l >> 4) * 8;
            float4 f0 = *(const float4*)(ap + 0);
            float4 f1 = *(const float4*)(ap + 4);
            a[0] = (short)f2b(f0.x); a[1] = (short)f2b(f0.y);
            a[2] = (short)f2b(f0.z); a[3] = (short)f2b(f0.w);
            a[4] = (short)f2b(f1.x); a[5] = (short)f2b(f1.y);
            a[6] = (short)f2b(f1.z); a[7] = (short)f2b(f1.w);
        } else {
            a = *(const short8*)((const unsigned short*)in_v + (size_t)arow * K + s * 32 + (l >> 4) * 8);
        }
        acc0 = __builtin_amdgcn_mfma_f32_16x16x32_bf16(a, WL[(0 * S + s) * 64 + l], acc0, 0, 0, 0);
        acc1 = __builtin_amdgcn_mfma_f32_16x16x32_bf16(a, WL[(1 * S + s) * 64 + l], acc1, 0, 0, 0);
        acc2 = __builtin_amdgcn_mfma_f32_16x16x32_bf16(a, WL[(2 * S + s) * 64 + l], acc2, 0, 0, 0);
        acc3 = __builtin_amdgcn_mfma_f32_16x16x32_bf16(a, WL[(3 * S + s) * 64 + l], acc3, 0, 0, 0);
    }

    #pragma unroll
    for (int j = 0; j < 4; ++j) {
        int row = rowBase + (l >> 4) * 4 + j;
        if (row >= rows) continue;
        unsigned short* orow = out + (size_t)row * H;
        float sc = SCALE ? scl[row] : 1.0f;
        float v;
        int col = l & 15;
        v = acc0[j] + (BIAS ? bias[col] : 0.f);      if (ACT) v = lrelu(v); orow[col]      = f2b(v * sc);
        v = acc1[j] + (BIAS ? bias[col + 16] : 0.f); if (ACT) v = lrelu(v); orow[col + 16] = f2b(v * sc);
        v = acc2[j] + (BIAS ? bias[col + 32] : 0.f); if (ACT) v = lrelu(v); orow[col + 32] = f2b(v * sc);
        v = acc3[j] + (BIAS ? bias[col + 48] : 0.f); if (ACT) v = lrelu(v); orow[col + 48] = f2b(v * sc);

        if (CLS) {
            // data rows in the meta graph have only their self loop (deg=1, dis=1):
            // out = log_softmax(lrelu(acc + clsBias) @ Wc + bc). All 16 lanes of this
            // row group take the same branch, so the shuffle reduce is safe.
            if (row < clsN) {
                float r0 = lrelu(acc0[j] + clsBias[col]);
                float r1 = lrelu(acc1[j] + clsBias[col + 16]);
                float r2 = lrelu(acc2[j] + clsBias[col + 32]);
                float r3 = lrelu(acc3[j] + clsBias[col + 48]);
                float p0 = r0 * Wc[col * 2]            + r1 * Wc[(col + 16) * 2]
                         + r2 * Wc[(col + 32) * 2]     + r3 * Wc[(col + 48) * 2];
                float p1 = r0 * Wc[col * 2 + 1]        + r1 * Wc[(col + 16) * 2 + 1]
                         + r2 * Wc[(col + 32) * 2 + 1] + r3 * Wc[(col + 48) * 2 + 1];
                #pragma unroll
                for (int o = 8; o; o >>= 1) {
                    p0 += __shfl_xor(p0, o);
                    p1 += __shfl_xor(p1, o);
                }
                if (col == 0) {
                    float l0 = p0 + bc[0], l1 = p1 + bc[1];
                    float m = fmaxf(l0, l1);
                    float lse = m + logf(expf(l0 - m) + expf(l1 - m));
                    fout[(size_t)row * 2 + 0] = l0 - lse;
                    fout[(size_t)row * 2 + 1] = l1 - lse;
                }
            }
        }
    }
}

// ---------------- combined bucket-sort CSR build (128-node buckets, data + meta) ----------------
// virtual bucket space: [0, nbD) data buckets (dst>>7), [nbD, nbD+nbM) meta buckets.
// packed entry = (dstLocal<<17) | src   (src < 2^17, dstLocal < 128)

__global__ __launch_bounds__(256) void zero_i(int* __restrict__ p, int n)
{
    int i = blockIdx.x * 256 + threadIdx.x;
    if (i < n) p[i] = 0;
}

__global__ __launch_bounds__(256) void bhist(const int* __restrict__ dstD, const int* __restrict__ dstM,
                                             int* __restrict__ gbh, int E, int Et, int nbD, int nbT)
{
    __shared__ int lh[NBMAX];
    for (int i = threadIdx.x; i < nbT; i += 256) lh[i] = 0;
    __syncthreads();
    for (int j = blockIdx.x * 256 + threadIdx.x; j < Et; j += 256 * gridDim.x) {
        int b = (j < E) ? (dstD[j] >> 7) : (nbD + (dstM[j - E] >> 7));
        atomicAdd(&lh[b], 1);
    }
    __syncthreads();
    for (int b = threadIdx.x; b < nbT; b += 256) {
        int v = lh[b];
        if (v) atomicAdd(&gbh[b], v);
    }
}

// single-block exclusive scan (nb <= 2048, 8 per thread)
__global__ __launch_bounds__(256) void bscan(const int* __restrict__ gbh, int* __restrict__ goff,
                                             int* __restrict__ gcur, int nb)
{
    __shared__ int sp[256];
    int t = threadIdx.x;
    int base = t * 8;
    int a[8];
    int s = 0;
    #pragma unroll
    for (int u = 0; u < 8; ++u) {
        a[u] = (base + u < nb) ? gbh[base + u] : 0;
        s += a[u];
    }
    sp[t] = s;
    __syncthreads();
    for (int o = 1; o < 256; o <<= 1) {
        int y = (t >= o) ? sp[t - o] : 0;
        __syncthreads();
        sp[t] += y;
        __syncthreads();
    }
    int e = sp[t] - s;
    #pragma unroll
    for (int u = 0; u < 8; ++u) {
        if (base + u < nb) { goff[base + u] = e; gcur[base + u] = e; }
        e += a[u];
    }
}

// direct rank-scatter over the combined edge list; edges cached in registers between passes
__global__ __launch_bounds__(256) void bfill(const int* __restrict__ srcD, const int* __restrict__ dstD,
                                             const int* __restrict__ srcM, const int* __restrict__ dstM,
                                             int* __restrict__ gcur, int* __restrict__ ebuf,
                                             int E, int Et, int nbD, int nbT)
{
    __shared__ int lh[NBMAX];
    __shared__ int lst[NBMAX];
    const int t = threadIdx.x;
    const int base = blockIdx.x * BTILE;

    for (int i = t; i < nbT; i += 256) lh[i] = 0;
    __syncthreads();

    int bb[8], pk[8];
    #pragma unroll
    for (int u = 0; u < 8; ++u) {
        int j = base + u * 256 + t;
        if (j < Et) {
            int d, sv;
            if (j < E) { d = dstD[j]; sv = srcD[j]; bb[u] = d >> 7; }
            else       { d = dstM[j - E]; sv = srcM[j - E]; bb[u] = nbD + (d >> 7); }
            pk[u] = ((d & 127) << 17) | sv;
            atomicAdd(&lh[bb[u]], 1);
        } else bb[u] = -1;
    }
    __syncthreads();

    for (int b = t; b < nbT; b += 256) {
        int k = lh[b];
        lst[b] = k ? atomicAdd(&gcur[b], k) : 0;
    }
    __syncthreads();

    #pragma unroll
    for (int u = 0; u < 8; ++u) {
        if (bb[u] >= 0) {
            int pos = atomicAdd(&lst[bb[u]], 1);
            ebuf[pos] = pk[u];
        }
    }
}

// block per bucket: local counting sort -> esrc (dense) + rs/cnt/dis in virtual node space
__global__ __launch_bounds__(256) void local_csr(const int* __restrict__ ebuf, const int* __restrict__ goff,
                                                 const int* __restrict__ gbh, int* __restrict__ esrc,
                                                 int* __restrict__ rs, int* __restrict__ cnt,
                                                 float* __restrict__ dis, int nbD, int N, int NM)
{
    __shared__ int lcnt[128];
    __shared__ int lrs[128];
    __shared__ int lcur[128];
    const int b = blockIdx.x;
    const int t = threadIdx.x;
    const int off = goff[b];
    const int k = gbh[b];
    const bool isData = b < nbD;

    if (t < 128) lcnt[t] = 0;
    __syncthreads();
    for (int i = t; i < k; i += 256) atomicAdd(&lcnt[ebuf[off + i] >> 17], 1);
    __syncthreads();
    if (t < 128) lrs[t] = lcnt[t];
    __syncthreads();
    for (int o = 1; o < 128; o <<= 1) {
        int y = (t < 128 && t >= o) ? lrs[t - o] : 0;
        __syncthreads();
        if (t < 128) lrs[t] += y;
        __syncthreads();
    }
    if (t < 128) lcur[t] = lrs[t] - lcnt[t];
    __syncthreads();
    for (int i = t; i < k; i += 256) {
        int v = ebuf[off + i];
        int dL = v >> 17;
        int pos = atomicAdd(&lcur[dL], 1);
        esrc[off + pos] = v & 0x1FFFF;
    }
    if (t < 128) {
        int local = isData ? b * 128 + t : (b - nbD) * 128 + t;
        int lim = isData ? N : NM;
        if (local < lim) {
            int slot = isData ? local : N + local;
            int c = lcnt[t];
            rs[slot] = off + (lrs[t] - c);
            cnt[slot] = c;
            int dt = c + (isData ? 1 : 0);
            dis[slot] = dt > 0 ? rsqrtf((float)dt) : 0.0f;
        }
    }
}

// ---- 16-lanes-per-dst gather, 4-deep unrolled: 16 dst rows per block ----
// h pre-scaled by dis[src]; out = lrelu(dd*(sum hs[s] (+hs[d] if SELF)) + bias)
template <bool SELF, bool FINAL>
__global__ __launch_bounds__(256) void gather16(const unsigned short* __restrict__ h,
                                                const int* __restrict__ esrc,
                                                const int* __restrict__ rs, const int* __restrict__ cnt,
                                                const float* __restrict__ dis, const float* __restrict__ bias,
                                                unsigned short* __restrict__ out,
                                                const float* __restrict__ Wc, const float* __restrict__ bc,
                                                float* __restrict__ fout, int base, int n)
{
    int d = base + blockIdx.x * 16 + (threadIdx.x >> 4);
    if (d >= n) return;
    const int l = threadIdx.x & 15;
    const int beg = rs[d];
    const int c = cnt[d];
    const float dd = dis[d];

    float ax0 = 0.f, ay0 = 0.f, az0 = 0.f, aw0 = 0.f;
    float ax1 = 0.f, ay1 = 0.f, az1 = 0.f, aw1 = 0.f;
    float ax2 = 0.f, ay2 = 0.f, az2 = 0.f, aw2 = 0.f;
    float ax3 = 0.f, ay3 = 0.f, az3 = 0.f, aw3 = 0.f;
    int i = 0;
    for (; i + 4 <= c; i += 4) {
        int s0 = esrc[beg + i], s1 = esrc[beg + i + 1];
        int s2 = esrc[beg + i + 2], s3 = esrc[beg + i + 3];
        ushort4 v0 = *(const ushort4*)(h + (size_t)s0 * H + l * 4);
        ushort4 v1 = *(const ushort4*)(h + (size_t)s1 * H + l * 4);
        ushort4 v2 = *(const ushort4*)(h + (size_t)s2 * H + l * 4);
        ushort4 v3 = *(const ushort4*)(h + (size_t)s3 * H + l * 4);
        ax0 += b2f(v0.x); ay0 += b2f(v0.y); az0 += b2f(v0.z); aw0 += b2f(v0.w);
        ax1 += b2f(v1.x); ay1 += b2f(v1.y); az1 += b2f(v1.z); aw1 += b2f(v1.w);
        ax2 += b2f(v2.x); ay2 += b2f(v2.y); az2 += b2f(v2.z); aw2 += b2f(v2.w);
        ax3 += b2f(v3.x); ay3 += b2f(v3.y); az3 += b2f(v3.z); aw3 += b2f(v3.w);
    }
    for (; i < c; ++i) {
        int s = esrc[beg + i];
        ushort4 v = *(const ushort4*)(h + (size_t)s * H + l * 4);
        ax0 += b2f(v.x); ay0 += b2f(v.y); az0 += b2f(v.z); aw0 += b2f(v.w);
    }
    if (SELF) {
        ushort4 v = *(const ushort4*)(h + (size_t)d * H + l * 4);
        ax0 += b2f(v.x); ay0 += b2f(v.y); az0 += b2f(v.z); aw0 += b2f(v.w);
    }

    float rx = ((ax0 + ax1) + (ax2 + ax3)) * dd;
    float ry = ((ay0 + ay1) + (ay2 + ay3)) * dd;
    float rz = ((az0 + az1) + (az2 + az3)) * dd;
    float rw = ((aw0 + aw1) + (aw2 + aw3)) * dd;
    float4 bb = *(const float4*)(bias + l * 4);
    rx = lrelu(rx + bb.x); ry = lrelu(ry + bb.y); rz = lrelu(rz + bb.z); rw = lrelu(rw + bb.w);

    if (FINAL) {
        int f = l * 4;
        float p0 = rx * Wc[(f + 0) * 2] + ry * Wc[(f + 1) * 2] + rz * Wc[(f + 2) * 2] + rw * Wc[(f + 3) * 2];
        float p1 = rx * Wc[(f + 0) * 2 + 1] + ry * Wc[(f + 1) * 2 + 1] + rz * Wc[(f + 2) * 2 + 1] + rw * Wc[(f + 3) * 2 + 1];
        #pragma unroll
        for (int o = 8; o; o >>= 1) {
            p0 += __shfl_xor(p0, o);
            p1 += __shfl_xor(p1, o);
        }
        if (l == 0) {
            float l0 = p0 + bc[0], l1 = p1 + bc[1];
            float m = fmaxf(l0, l1);
            float lse = m + logf(expf(l0 - m) + expf(l1 - m));
            fout[(size_t)d * 2 + 0] = l0 - lse;
            fout[(size_t)d * 2 + 1] = l1 - lse;
        }
    } else {
        ushort4 o;
        o.x = f2b(rx); o.y = f2b(ry); o.z = f2b(rz); o.w = f2b(rw);
        *(ushort4*)(out + (size_t)d * H + l * 4) = o;
    }
}

extern "C" void kernel_launch(void* const* d_in, const int* in_sizes, int n_in,
                              void* d_out, int out_size, void* d_ws, size_t ws_size,
                              hipStream_t stream)
{
    const float* x      = (const float*)d_in[0];
    const int*   ei     = (const int*)d_in[1];
    const float* mx     = (const float*)d_in[2];
    const int*   mei    = (const int*)d_in[3];
    const float* W_lin  = (const float*)d_in[4];
    const float* b_lin  = (const float*)d_in[5];
    const float* W_mlin = (const float*)d_in[6];
    const float* b_mlin = (const float*)d_in[7];
    const float* W0     = (const float*)d_in[8];
    const float* b0     = (const float*)d_in[9];
    const float* W1     = (const float*)d_in[10];
    const float* b1     = (const float*)d_in[11];
    const float* Wm     = (const float*)d_in[12];
    const float* bm     = (const float*)d_in[13];
    const float* Wc     = (const float*)d_in[14];
    const float* bc     = (const float*)d_in[15];

    const int F  = 128;
    const int N  = in_sizes[0] / F;
    const int E  = in_sizes[1] / 2;
    const int M  = in_sizes[2] / F;
    const int Em = in_sizes[3] / 2;
    const int NM = N + M;
    const int Et = E + Em;
    const int* src  = ei;
    const int* dstp = ei + E;
    const int* msrc = mei;
    const int* mdst = mei + Em;

    unsigned short* hb0 = (unsigned short*)d_ws;        // [NM, H] bf16
    unsigned short* hb1 = hb0 + (size_t)NM * H;         // [NM, H] bf16
    float* disV = (float*)(hb1 + (size_t)NM * H);       // [N + NM]
    int*   cntV = (int*)(disV + (N + NM));              // [N + NM]
    int*   rsV  = cntV + (N + NM);                      // [N + NM]
    int*   esrcA = rsV + (N + NM);                      // [Et]
    int*   ebuf  = esrcA + Et;                          // [Et]
    int*   gbh  = ebuf + Et;                            // [NBMAX]
    int*   goff = gbh + NBMAX;                          // [NBMAX]
    int*   gcur = goff + NBMAX;                         // [NBMAX]

    const int nbD = (N + 127) / 128;
    const int nbM = (NM + 127) / 128;
    const int nbT = nbD + nbM;

    // input projections (meta rows go straight to concat slot)
    mfma_gemm<128, true, true, true, false, false><<<(N + 63) / 64, 256, 0, stream>>>(
        x, W_lin, b_lin, nullptr, hb0, N, nullptr, nullptr, nullptr, nullptr, 0);
    mfma_gemm<128, true, true, true, false, false><<<(M + 63) / 64, 256, 0, stream>>>(
        mx, W_mlin, b_mlin, nullptr, hb0 + (size_t)N * H, M, nullptr, nullptr, nullptr, nullptr, 0);

    // combined CSR build (data + meta graphs in one pass)
    zero_i<<<(NBMAX + 255) / 256, 256, 0, stream>>>(gbh, NBMAX);
    bhist<<<256, 256, 0, stream>>>(dstp, mdst, gbh, E, Et, nbD, nbT);
    bscan<<<1, 256, 0, stream>>>(gbh, goff, gcur, nbT);
    bfill<<<(Et + BTILE - 1) / BTILE, 256, 0, stream>>>(src, dstp, msrc, mdst, gcur, ebuf, E, Et, nbD, nbT);
    local_csr<<<nbT, 256, 0, stream>>>(ebuf, goff, gbh, esrcA, rsV, cntV, disV, nbD, N, NM);

    // GCN layer 0 (GEMM output pre-scaled by dis)
    mfma_gemm<64, false, false, false, true, false><<<(N + 63) / 64, 256, 0, stream>>>(
        hb0, W0, nullptr, disV, hb1, N, nullptr, nullptr, nullptr, nullptr, 0);
    gather16<true, false><<<(N + 15) / 16, 256, 0, stream>>>(
        hb1, esrcA, rsV, cntV, disV, b0, hb0, nullptr, nullptr, nullptr, 0, N);

    // GCN layer 1
    mfma_gemm<64, false, false, false, true, false><<<(N + 63) / 64, 256, 0, stream>>>(
        hb0, W1, nullptr, disV, hb1, N, nullptr, nullptr, nullptr, nullptr, 0);
    gather16<true, false><<<(N + 15) / 16, 256, 0, stream>>>(
        hb1, esrcA, rsV, cntV, disV, b1, hb0, nullptr, nullptr, nullptr, 0, N);

    // meta fusion GEMM over z = hb0[0..NM), pre-scaled by meta dis.
    // Data rows (< N) have deg=1 self-loop in the meta graph (dis=1), so their final
    // output is log_softmax(lrelu(acc + bm) @ Wc + bc) — fused into this epilogue.
    mfma_gemm<64, false, false, false, true, true><<<(NM + 63) / 64, 256, 0, stream>>>(
        hb0, Wm, nullptr, disV + N, hb1, NM, bm, Wc, bc, (float*)d_out, N);

    // final gather + fused classifier + log_softmax over META nodes only (d in [N, NM))
    gather16<false, true><<<(M + 15) / 16, 256, 0, stream>>>(
        hb1, esrcA, rsV + N, cntV + N, disV + N, bm, nullptr, Wc, bc, (float*)d_out, N, NM);
}